// Round 2
// baseline (1436.438 us; speedup 1.0000x reference)
//
#include <hip/hip_runtime.h>
#include <hip/hip_bf16.h>

#define TPB 256

// Kernel 1: xl = x @ W1 + b1  (f32); also agg = xl (self-loop init)
__global__ __launch_bounds__(TPB) void k_gemm1(
    const float* __restrict__ x,   // [N,128]
    const float* __restrict__ W1,  // [128,64]
    const float* __restrict__ b1,  // [64]
    float* __restrict__ xl, float* __restrict__ agg, int N)
{
    __shared__ float w1s[128 * 64];   // 32 KB
    __shared__ float xs[64 * 132];    // padded stride 132 (2-way LDS alias = free)
    __shared__ float b1s[64];

    const int t = threadIdx.x;
    const int rbase = blockIdx.x * 64;
    const int rows = min(64, N - rbase);

    // stage W1 (8192 f32 = 2048 float4), coalesced
    const float4* w4 = reinterpret_cast<const float4*>(W1);
    for (int i = t; i < 2048; i += TPB) {
        float4 u = w4[i];
        int o = i * 4;
        w1s[o+0] = u.x; w1s[o+1] = u.y; w1s[o+2] = u.z; w1s[o+3] = u.w;
    }
    if (t < 64) b1s[t] = b1[t];

    // stage x tile (rows x 128 f32), coalesced float4
    const float4* x4 = reinterpret_cast<const float4*>(x);
    for (int i = t; i < rows * 32; i += TPB) {
        float4 u = x4[(size_t)rbase * 32 + i];
        int row = i >> 5, kk = (i & 31) * 4;
        float* p = &xs[row * 132 + kk];
        p[0] = u.x; p[1] = u.y; p[2] = u.z; p[3] = u.w;
    }
    __syncthreads();

    // 4 threads per row, 16 cols each
    const int row = t >> 2, cg = t & 3;
    if (row < rows) {
        float acc[16];
        #pragma unroll
        for (int c = 0; c < 16; c++) acc[c] = b1s[cg*16 + c];
        const float* xr = &xs[row * 132];
        #pragma unroll 4
        for (int k = 0; k < 128; k++) {
            float a = xr[k];
            const float* wp = &w1s[k*64 + cg*16];
            #pragma unroll
            for (int c = 0; c < 16; c++) acc[c] = fmaf(a, wp[c], acc[c]);
        }
        size_t o = (size_t)(rbase + row) * 64 + cg * 16;
        float4* xo = reinterpret_cast<float4*>(xl + o);
        float4* ao = reinterpret_cast<float4*>(agg + o);
        #pragma unroll
        for (int j = 0; j < 4; j++) {
            float4 v = make_float4(acc[j*4+0], acc[j*4+1], acc[j*4+2], acc[j*4+3]);
            xo[j] = v;
            ao[j] = v;
        }
    }
}

// Kernel 2: agg[dst] += xl[src] over all edges. 16 threads/edge, float4 each.
__global__ __launch_bounds__(TPB) void k_scatter(
    const int* __restrict__ ei,        // [2,E]: src = ei[0:E], dst = ei[E:2E]
    const float* __restrict__ xl,
    float* __restrict__ agg, int E)
{
    int idx = blockIdx.x * TPB + threadIdx.x;   // up to 25.6M, fits int32
    int e = idx >> 4;
    if (e >= E) return;
    int g = idx & 15;
    int s = ei[e], d = ei[E + e];
    float4 v = reinterpret_cast<const float4*>(xl)[(size_t)s * 16 + g];
    float* p = agg + (size_t)d * 64 + (size_t)g * 4;
    // hardware global_atomic_add_f32 (plain atomicAdd may fall to CAS loop)
    unsafeAtomicAdd(p + 0, v.x);
    unsafeAtomicAdd(p + 1, v.y);
    unsafeAtomicAdd(p + 2, v.z);
    unsafeAtomicAdd(p + 3, v.w);
}

// Kernel 3: out = relu(agg) @ W2 + b2  (f32 out)
__global__ __launch_bounds__(TPB) void k_gemm2(
    const float* __restrict__ agg,
    const float* __restrict__ W2,  // [64,32]
    const float* __restrict__ b2,  // [32]
    float* __restrict__ out, int N)
{
    __shared__ float w2s[64 * 32];   // 8 KB
    __shared__ float as[64 * 68];    // padded stride 68 (2-way alias = free)
    __shared__ float b2s[32];

    const int t = threadIdx.x;
    const int rbase = blockIdx.x * 64;
    const int rows = min(64, N - rbase);

    const float4* w4 = reinterpret_cast<const float4*>(W2);
    for (int i = t; i < 512; i += TPB) {
        float4 u = w4[i];
        int o = i * 4;
        w2s[o+0] = u.x; w2s[o+1] = u.y; w2s[o+2] = u.z; w2s[o+3] = u.w;
    }
    if (t < 32) b2s[t] = b2[t];

    // stage agg tile with fused relu, coalesced float4
    const float4* a4 = reinterpret_cast<const float4*>(agg + (size_t)rbase * 64);
    for (int i = t; i < rows * 16; i += TPB) {
        float4 v = a4[i];
        int row = i >> 4, kk = (i & 15) * 4;
        float* p = &as[row * 68 + kk];
        p[0] = fmaxf(v.x, 0.f); p[1] = fmaxf(v.y, 0.f);
        p[2] = fmaxf(v.z, 0.f); p[3] = fmaxf(v.w, 0.f);
    }
    __syncthreads();

    const int row = t >> 2, cg = t & 3;   // 4 threads/row, 8 cols each
    if (row < rows) {
        float acc[8];
        #pragma unroll
        for (int c = 0; c < 8; c++) acc[c] = b2s[cg*8 + c];
        const float* ar = &as[row * 68];
        #pragma unroll 4
        for (int k = 0; k < 64; k++) {
            float a = ar[k];
            const float* wp = &w2s[k*32 + cg*8];
            #pragma unroll
            for (int c = 0; c < 8; c++) acc[c] = fmaf(a, wp[c], acc[c]);
        }
        float4* op = reinterpret_cast<float4*>(out + (size_t)(rbase + row) * 32 + cg * 8);
        op[0] = make_float4(acc[0], acc[1], acc[2], acc[3]);
        op[1] = make_float4(acc[4], acc[5], acc[6], acc[7]);
    }
}

extern "C" void kernel_launch(void* const* d_in, const int* in_sizes, int n_in,
                              void* d_out, int out_size, void* d_ws, size_t ws_size,
                              hipStream_t stream) {
    const float* x  = (const float*)d_in[0];
    const int*   ei = (const int*)d_in[1];
    const float* W1 = (const float*)d_in[2];
    const float* b1 = (const float*)d_in[3];
    const float* W2 = (const float*)d_in[4];
    const float* b2 = (const float*)d_in[5];
    float* out = (float*)d_out;

    const int N = in_sizes[0] / 128;
    const int E = in_sizes[1] / 2;

    float* xl  = (float*)d_ws;                 // [N,64] f32 = 25.6 MB
    float* agg = xl + (size_t)N * 64;          // [N,64] f32 = 25.6 MB (ws >= 51.2 MB)

    const int nb = (N + 63) / 64;
    hipLaunchKernelGGL(k_gemm1, dim3(nb), dim3(TPB), 0, stream, x, W1, b1, xl, agg, N);

    const int sb = (E * 16 + TPB - 1) / TPB;
    hipLaunchKernelGGL(k_scatter, dim3(sb), dim3(TPB), 0, stream, ei, xl, agg, E);

    hipLaunchKernelGGL(k_gemm2, dim3(nb), dim3(TPB), 0, stream, agg, W2, b2, out, N);
}

// Round 3
// 360.153 us; speedup vs baseline: 3.9884x; 3.9884x over previous
//
#include <hip/hip_runtime.h>
#include <hip/hip_bf16.h>

#define TPB 256

// ---------------- Kernel 1: xl = x @ W1 + b1 (f32) ----------------
__global__ __launch_bounds__(TPB) void k_gemm1(
    const float* __restrict__ x,   // [N,128]
    const float* __restrict__ W1,  // [128,64]
    const float* __restrict__ b1,  // [64]
    float* __restrict__ xl, int N)
{
    __shared__ float w1s[128 * 64];   // 32 KB
    __shared__ float xs[64 * 132];    // padded stride 132 (2-way alias = free)
    __shared__ float b1s[64];

    const int t = threadIdx.x;
    const int rbase = blockIdx.x * 64;
    const int rows = min(64, N - rbase);

    const float4* w4 = reinterpret_cast<const float4*>(W1);
    for (int i = t; i < 2048; i += TPB) {
        float4 u = w4[i];
        int o = i * 4;
        w1s[o+0] = u.x; w1s[o+1] = u.y; w1s[o+2] = u.z; w1s[o+3] = u.w;
    }
    if (t < 64) b1s[t] = b1[t];

    const float4* x4 = reinterpret_cast<const float4*>(x);
    for (int i = t; i < rows * 32; i += TPB) {
        float4 u = x4[(size_t)rbase * 32 + i];
        int row = i >> 5, kk = (i & 31) * 4;
        float* p = &xs[row * 132 + kk];
        p[0] = u.x; p[1] = u.y; p[2] = u.z; p[3] = u.w;
    }
    __syncthreads();

    const int row = t >> 2, cg = t & 3;   // 4 threads/row, 16 cols each
    if (row < rows) {
        float acc[16];
        #pragma unroll
        for (int c = 0; c < 16; c++) acc[c] = b1s[cg*16 + c];
        const float* xr = &xs[row * 132];
        #pragma unroll 4
        for (int k = 0; k < 128; k++) {
            float a = xr[k];
            const float* wp = &w1s[k*64 + cg*16];
            #pragma unroll
            for (int c = 0; c < 16; c++) acc[c] = fmaf(a, wp[c], acc[c]);
        }
        float4* xo = reinterpret_cast<float4*>(xl + (size_t)(rbase + row) * 64 + cg * 16);
        #pragma unroll
        for (int j = 0; j < 4; j++)
            xo[j] = make_float4(acc[j*4+0], acc[j*4+1], acc[j*4+2], acc[j*4+3]);
    }
}

// ---------------- CSR build ----------------
// histogram of dst
__global__ __launch_bounds__(TPB) void k_hist(
    const int* __restrict__ ei, int* __restrict__ counts, int E)
{
    int i = blockIdx.x * TPB + threadIdx.x;
    if (i < E) atomicAdd(&counts[ei[E + i]], 1);
}

// block-level scan: 256 threads x 8 elems = 2048/block.
// writes per-block-exclusive prefix into off[], block total into blksums[].
#define SCAN_CHUNK 8
#define SCAN_ELEMS (TPB * SCAN_CHUNK)
__global__ __launch_bounds__(TPB) void k_scan1(
    const int* __restrict__ counts, int* __restrict__ off,
    int* __restrict__ blksums, int N)
{
    __shared__ int wsum[4];
    const int t = threadIdx.x;
    const int base = blockIdx.x * SCAN_ELEMS + t * SCAN_CHUNK;
    int v[SCAN_CHUNK];
    #pragma unroll
    for (int j = 0; j < SCAN_CHUNK; j++)
        v[j] = (base + j < N) ? counts[base + j] : 0;
    int tsum = 0;
    #pragma unroll
    for (int j = 0; j < SCAN_CHUNK; j++) { int a = v[j]; v[j] = tsum; tsum += a; }
    // wave inclusive scan of tsum
    const int lane = t & 63, wid = t >> 6;
    int incl = tsum;
    for (int d = 1; d < 64; d <<= 1) {
        int n = __shfl_up(incl, d);
        if (lane >= d) incl += n;
    }
    if (lane == 63) wsum[wid] = incl;
    __syncthreads();
    int woff = 0;
    for (int w = 0; w < wid; w++) woff += wsum[w];
    const int texcl = woff + incl - tsum;   // exclusive prefix for this thread
    #pragma unroll
    for (int j = 0; j < SCAN_CHUNK; j++)
        if (base + j < N) off[base + j] = v[j] + texcl;
    if (t == TPB - 1) blksums[blockIdx.x] = woff + incl;
}

// serial exclusive scan of block sums (nb ~ 49)
__global__ void k_scan2(int* blksums, int nb)
{
    if (threadIdx.x == 0 && blockIdx.x == 0) {
        int run = 0;
        for (int i = 0; i < nb; i++) { int v = blksums[i]; blksums[i] = run; run += v; }
    }
}

// add block offsets; duplicate into cursor array; set off[N]=E
__global__ __launch_bounds__(TPB) void k_scan3(
    int* __restrict__ off, const int* __restrict__ blksums,
    int* __restrict__ cur, int N, int E)
{
    int i = blockIdx.x * TPB + threadIdx.x;
    if (i < N) {
        int v = off[i] + blksums[i / SCAN_ELEMS];
        off[i] = v;
        cur[i] = v;
    }
    if (i == 0) off[N] = E;
}

// fill CSR edge array: esrc[pos] = src for each edge grouped by dst
__global__ __launch_bounds__(TPB) void k_fill(
    const int* __restrict__ ei, int* __restrict__ cur,
    int* __restrict__ esrc, int E)
{
    int i = blockIdx.x * TPB + threadIdx.x;
    if (i >= E) return;
    int s = ei[i], d = ei[E + i];
    int pos = atomicAdd(&cur[d], 1);
    esrc[pos] = s;
}

// ---------------- Aggregate + ReLU + GEMM2 fused ----------------
// one wave per node: 4 edge-slots x 16 quad-lanes gather float4 from xl[src];
// shuffle-reduce, add self-loop, relu -> wave-private LDS row -> gemm2 -> out
#define AGG_BLOCKS 2048
__global__ __launch_bounds__(TPB) void k_agg(
    const float* __restrict__ xl,    // [N,64]
    const int* __restrict__ off,     // [N+1]
    const int* __restrict__ esrc,    // [E]
    const float* __restrict__ W2,    // [64,32]
    const float* __restrict__ b2,    // [32]
    float* __restrict__ out, int N)
{
    __shared__ float w2s[64 * 32];   // 8 KB
    __shared__ float b2s[32];
    __shared__ float arow[4][68];    // wave-private agg row (pad to 68)

    const int t = threadIdx.x;
    const float4* w4 = reinterpret_cast<const float4*>(W2);
    for (int i = t; i < 512; i += TPB) {
        float4 u = w4[i];
        int o = i * 4;
        w2s[o+0] = u.x; w2s[o+1] = u.y; w2s[o+2] = u.z; w2s[o+3] = u.w;
    }
    if (t < 32) b2s[t] = b2[t];
    __syncthreads();

    const int wid = t >> 6, lane = t & 63;
    const int eslot = lane >> 4, q = lane & 15;   // 4 edge slots x 16 quads
    const int c = lane & 31, h = lane >> 5;       // gemm2 mapping
    const float4* xl4 = reinterpret_cast<const float4*>(xl);

    for (int node = blockIdx.x * 4 + wid; node < N; node += gridDim.x * 4) {
        const int beg = off[node], end = off[node + 1];
        float4 acc = make_float4(0.f, 0.f, 0.f, 0.f);
        for (int e = beg + eslot; e < end; e += 4) {
            int s = esrc[e];
            float4 v = xl4[(size_t)s * 16 + q];
            acc.x += v.x; acc.y += v.y; acc.z += v.z; acc.w += v.w;
        }
        // reduce across the 4 edge slots (lanes differing in bits 4,5)
        acc.x += __shfl_xor(acc.x, 16); acc.y += __shfl_xor(acc.y, 16);
        acc.z += __shfl_xor(acc.z, 16); acc.w += __shfl_xor(acc.w, 16);
        acc.x += __shfl_xor(acc.x, 32); acc.y += __shfl_xor(acc.y, 32);
        acc.z += __shfl_xor(acc.z, 32); acc.w += __shfl_xor(acc.w, 32);
        if (eslot == 0) {
            float4 sv = xl4[(size_t)node * 16 + q];   // self-loop
            float* p = &arow[wid][q * 4];
            p[0] = fmaxf(acc.x + sv.x, 0.f);
            p[1] = fmaxf(acc.y + sv.y, 0.f);
            p[2] = fmaxf(acc.z + sv.z, 0.f);
            p[3] = fmaxf(acc.w + sv.w, 0.f);
        }
        // same-wave LDS RAW: compiler inserts lgkmcnt wait before dependent read
        float o = 0.f;
        const float* ar = &arow[wid][h * 32];
        const float* wp = &w2s[h * 32 * 32 + c];
        #pragma unroll
        for (int kk = 0; kk < 32; kk++)
            o = fmaf(ar[kk], wp[kk * 32], o);
        o += __shfl_xor(o, 32);
        if (h == 0) out[(size_t)node * 32 + c] = o + b2s[c];
    }
}

extern "C" void kernel_launch(void* const* d_in, const int* in_sizes, int n_in,
                              void* d_out, int out_size, void* d_ws, size_t ws_size,
                              hipStream_t stream) {
    const float* x  = (const float*)d_in[0];
    const int*   ei = (const int*)d_in[1];
    const float* W1 = (const float*)d_in[2];
    const float* b1 = (const float*)d_in[3];
    const float* W2 = (const float*)d_in[4];
    const float* b2 = (const float*)d_in[5];
    float* out = (float*)d_out;

    const int N = in_sizes[0] / 128;
    const int E = in_sizes[1] / 2;

    // workspace layout (16B-aligned chunks)
    char* w = (char*)d_ws;
    float* xl     = (float*)w;                 w += (size_t)N * 64 * 4;   // 25.6 MB
    int*   counts = (int*)w;                   w += ((size_t)N * 4 + 15) & ~15ull;
    int*   off    = (int*)w;                   w += ((size_t)(N + 1) * 4 + 15) & ~15ull;
    int*   cur    = (int*)w;                   w += ((size_t)N * 4 + 15) & ~15ull;
    int*   blksums= (int*)w;                   w += 4096;
    int*   esrc   = (int*)w;                   // E*4 = 6.4 MB

    const int nb  = (N + 63) / 64;
    const int eb  = (E + TPB - 1) / TPB;
    const int nb1 = (N + SCAN_ELEMS - 1) / SCAN_ELEMS;
    const int nbt = (N + TPB - 1) / TPB;

    hipMemsetAsync(counts, 0, (size_t)N * 4, stream);
    hipLaunchKernelGGL(k_gemm1, dim3(nb), dim3(TPB), 0, stream, x, W1, b1, xl, N);
    hipLaunchKernelGGL(k_hist,  dim3(eb), dim3(TPB), 0, stream, ei, counts, E);
    hipLaunchKernelGGL(k_scan1, dim3(nb1), dim3(TPB), 0, stream, counts, off, blksums, N);
    hipLaunchKernelGGL(k_scan2, dim3(1), dim3(64), 0, stream, blksums, nb1);
    hipLaunchKernelGGL(k_scan3, dim3(nbt), dim3(TPB), 0, stream, off, blksums, cur, N, E);
    hipLaunchKernelGGL(k_fill,  dim3(eb), dim3(TPB), 0, stream, ei, cur, esrc, E);
    hipLaunchKernelGGL(k_agg,   dim3(AGG_BLOCKS), dim3(TPB), 0, stream,
                       xl, off, esrc, W2, b2, out, N);
}

// Round 4
// 299.124 us; speedup vs baseline: 4.8021x; 1.2040x over previous
//
#include <hip/hip_runtime.h>
#include <hip/hip_bf16.h>

#define TPB 256
#define NXCD 8

// ---------------- Kernel 1: xl = x @ W1 + b1 (f32) ----------------
__global__ __launch_bounds__(TPB) void k_gemm1(
    const float* __restrict__ x,   // [N,128]
    const float* __restrict__ W1,  // [128,64]
    const float* __restrict__ b1,  // [64]
    float* __restrict__ xl, int N)
{
    __shared__ float w1s[128 * 64];   // 32 KB
    __shared__ float xs[64 * 132];    // padded stride 132 (2-way alias = free)
    __shared__ float b1s[64];

    const int t = threadIdx.x;
    const int rbase = blockIdx.x * 64;
    const int rows = min(64, N - rbase);

    const float4* w4 = reinterpret_cast<const float4*>(W1);
    for (int i = t; i < 2048; i += TPB) {
        float4 u = w4[i];
        int o = i * 4;
        w1s[o+0] = u.x; w1s[o+1] = u.y; w1s[o+2] = u.z; w1s[o+3] = u.w;
    }
    if (t < 64) b1s[t] = b1[t];

    const float4* x4 = reinterpret_cast<const float4*>(x);
    for (int i = t; i < rows * 32; i += TPB) {
        float4 u = x4[(size_t)rbase * 32 + i];
        int row = i >> 5, kk = (i & 31) * 4;
        float* p = &xs[row * 132 + kk];
        p[0] = u.x; p[1] = u.y; p[2] = u.z; p[3] = u.w;
    }
    __syncthreads();

    const int row = t >> 2, cg = t & 3;   // 4 threads/row, 16 cols each
    if (row < rows) {
        float acc[16];
        #pragma unroll
        for (int c = 0; c < 16; c++) acc[c] = b1s[cg*16 + c];
        const float* xr = &xs[row * 132];
        #pragma unroll 4
        for (int k = 0; k < 128; k++) {
            float a = xr[k];
            const float* wp = &w1s[k*64 + cg*16];
            #pragma unroll
            for (int c = 0; c < 16; c++) acc[c] = fmaf(a, wp[c], acc[c]);
        }
        float4* xo = reinterpret_cast<float4*>(xl + (size_t)(rbase + row) * 64 + cg * 16);
        #pragma unroll
        for (int j = 0; j < 4; j++)
            xo[j] = make_float4(acc[j*4+0], acc[j*4+1], acc[j*4+2], acc[j*4+3]);
    }
}

// ---------------- CSR build, XCD-slice-privatized ----------------
// Group g = blockIdx & 7 (round-robin dispatch -> XCD g) handles only
// dst in [g*slice, (g+1)*slice): its counter/cursor/esrc lines stay in
// ONE XCD's L2 -> no cross-XCD dirty-line ping-pong (was 16x write amp).
// Correct regardless of actual block->XCD placement (atomics are device-scope).
__global__ __launch_bounds__(TPB) void k_hist(
    const int* __restrict__ ei, int* __restrict__ counts, int E, int N)
{
    const int slice = (N + NXCD - 1) / NXCD;
    const int g = blockIdx.x & (NXCD - 1);
    const int kb = blockIdx.x >> 3;
    const int K = gridDim.x >> 3;
    const int lo = g * slice, hi = min(N, lo + slice);
    for (int i = kb * TPB + threadIdx.x; i < E; i += K * TPB) {
        int d = ei[E + i];
        if (d >= lo && d < hi) atomicAdd(&counts[d], 1);
    }
}

// block-level scan: 256 threads x 8 elems = 2048/block.
#define SCAN_CHUNK 8
#define SCAN_ELEMS (TPB * SCAN_CHUNK)
__global__ __launch_bounds__(TPB) void k_scan1(
    const int* __restrict__ counts, int* __restrict__ off,
    int* __restrict__ blksums, int N)
{
    __shared__ int wsum[4];
    const int t = threadIdx.x;
    const int base = blockIdx.x * SCAN_ELEMS + t * SCAN_CHUNK;
    int v[SCAN_CHUNK];
    #pragma unroll
    for (int j = 0; j < SCAN_CHUNK; j++)
        v[j] = (base + j < N) ? counts[base + j] : 0;
    int tsum = 0;
    #pragma unroll
    for (int j = 0; j < SCAN_CHUNK; j++) { int a = v[j]; v[j] = tsum; tsum += a; }
    const int lane = t & 63, wid = t >> 6;
    int incl = tsum;
    for (int d = 1; d < 64; d <<= 1) {
        int n = __shfl_up(incl, d);
        if (lane >= d) incl += n;
    }
    if (lane == 63) wsum[wid] = incl;
    __syncthreads();
    int woff = 0;
    for (int w = 0; w < wid; w++) woff += wsum[w];
    const int texcl = woff + incl - tsum;
    #pragma unroll
    for (int j = 0; j < SCAN_CHUNK; j++)
        if (base + j < N) off[base + j] = v[j] + texcl;
    if (t == TPB - 1) blksums[blockIdx.x] = woff + incl;
}

__global__ void k_scan2(int* blksums, int nb)
{
    if (threadIdx.x == 0 && blockIdx.x == 0) {
        int run = 0;
        for (int i = 0; i < nb; i++) { int v = blksums[i]; blksums[i] = run; run += v; }
    }
}

__global__ __launch_bounds__(TPB) void k_scan3(
    int* __restrict__ off, const int* __restrict__ blksums,
    int* __restrict__ cur, int N, int E)
{
    int i = blockIdx.x * TPB + threadIdx.x;
    if (i < N) {
        int v = off[i] + blksums[i / SCAN_ELEMS];
        off[i] = v;
        cur[i] = v;
    }
    if (i == 0) off[N] = E;
}

// fill CSR edge array, slice-privatized like k_hist. esrc positions for
// slice g are contiguous (CSR offsets sorted by node) -> 0.8 MB L2-resident.
__global__ __launch_bounds__(TPB) void k_fill(
    const int* __restrict__ ei, int* __restrict__ cur,
    int* __restrict__ esrc, int E, int N)
{
    const int slice = (N + NXCD - 1) / NXCD;
    const int g = blockIdx.x & (NXCD - 1);
    const int kb = blockIdx.x >> 3;
    const int K = gridDim.x >> 3;
    const int lo = g * slice, hi = min(N, lo + slice);
    for (int i = kb * TPB + threadIdx.x; i < E; i += K * TPB) {
        int d = ei[E + i];
        if (d >= lo && d < hi) {
            int s = ei[i];
            int pos = atomicAdd(&cur[d], 1);
            esrc[pos] = s;
        }
    }
}

// ---------------- Aggregate + ReLU + GEMM2 fused ----------------
#define AGG_BLOCKS 2048
__global__ __launch_bounds__(TPB) void k_agg(
    const float* __restrict__ xl,    // [N,64]
    const int* __restrict__ off,     // [N+1]
    const int* __restrict__ esrc,    // [E]
    const float* __restrict__ W2,    // [64,32]
    const float* __restrict__ b2,    // [32]
    float* __restrict__ out, int N)
{
    __shared__ float w2s[64 * 32];   // 8 KB
    __shared__ float b2s[32];
    __shared__ float arow[4][68];    // wave-private agg row (pad to 68)

    const int t = threadIdx.x;
    const float4* w4 = reinterpret_cast<const float4*>(W2);
    for (int i = t; i < 512; i += TPB) {
        float4 u = w4[i];
        int o = i * 4;
        w2s[o+0] = u.x; w2s[o+1] = u.y; w2s[o+2] = u.z; w2s[o+3] = u.w;
    }
    if (t < 32) b2s[t] = b2[t];
    __syncthreads();

    const int wid = t >> 6, lane = t & 63;
    const int eslot = lane >> 4, q = lane & 15;   // 4 edge slots x 16 quads
    const int c = lane & 31, h = lane >> 5;       // gemm2 mapping
    const float4* xl4 = reinterpret_cast<const float4*>(xl);

    for (int node = blockIdx.x * 4 + wid; node < N; node += gridDim.x * 4) {
        const int beg = off[node], end = off[node + 1];
        float4 acc = make_float4(0.f, 0.f, 0.f, 0.f);
        for (int e = beg + eslot; e < end; e += 4) {
            int s = esrc[e];
            float4 v = xl4[(size_t)s * 16 + q];
            acc.x += v.x; acc.y += v.y; acc.z += v.z; acc.w += v.w;
        }
        acc.x += __shfl_xor(acc.x, 16); acc.y += __shfl_xor(acc.y, 16);
        acc.z += __shfl_xor(acc.z, 16); acc.w += __shfl_xor(acc.w, 16);
        acc.x += __shfl_xor(acc.x, 32); acc.y += __shfl_xor(acc.y, 32);
        acc.z += __shfl_xor(acc.z, 32); acc.w += __shfl_xor(acc.w, 32);
        if (eslot == 0) {
            float4 sv = xl4[(size_t)node * 16 + q];   // self-loop
            float* p = &arow[wid][q * 4];
            p[0] = fmaxf(acc.x + sv.x, 0.f);
            p[1] = fmaxf(acc.y + sv.y, 0.f);
            p[2] = fmaxf(acc.z + sv.z, 0.f);
            p[3] = fmaxf(acc.w + sv.w, 0.f);
        }
        float o = 0.f;
        const float* ar = &arow[wid][h * 32];
        const float* wp = &w2s[h * 32 * 32 + c];
        #pragma unroll
        for (int kk = 0; kk < 32; kk++)
            o = fmaf(ar[kk], wp[kk * 32], o);
        o += __shfl_xor(o, 32);
        if (h == 0) out[(size_t)node * 32 + c] = o + b2s[c];
    }
}

extern "C" void kernel_launch(void* const* d_in, const int* in_sizes, int n_in,
                              void* d_out, int out_size, void* d_ws, size_t ws_size,
                              hipStream_t stream) {
    const float* x  = (const float*)d_in[0];
    const int*   ei = (const int*)d_in[1];
    const float* W1 = (const float*)d_in[2];
    const float* b1 = (const float*)d_in[3];
    const float* W2 = (const float*)d_in[4];
    const float* b2 = (const float*)d_in[5];
    float* out = (float*)d_out;

    const int N = in_sizes[0] / 128;
    const int E = in_sizes[1] / 2;

    char* w = (char*)d_ws;
    float* xl     = (float*)w;                 w += (size_t)N * 64 * 4;   // 25.6 MB
    int*   counts = (int*)w;                   w += ((size_t)N * 4 + 15) & ~15ull;
    int*   off    = (int*)w;                   w += ((size_t)(N + 1) * 4 + 15) & ~15ull;
    int*   cur    = (int*)w;                   w += ((size_t)N * 4 + 15) & ~15ull;
    int*   blksums= (int*)w;                   w += 4096;
    int*   esrc   = (int*)w;                   // E*4 = 6.4 MB

    const int nb  = (N + 63) / 64;
    const int nb1 = (N + SCAN_ELEMS - 1) / SCAN_ELEMS;
    const int nbt = (N + TPB - 1) / TPB;
    const int pb  = 2048;   // privatized kernels: 8 groups x 256 blocks

    hipMemsetAsync(counts, 0, (size_t)N * 4, stream);
    hipLaunchKernelGGL(k_gemm1, dim3(nb), dim3(TPB), 0, stream, x, W1, b1, xl, N);
    hipLaunchKernelGGL(k_hist,  dim3(pb), dim3(TPB), 0, stream, ei, counts, E, N);
    hipLaunchKernelGGL(k_scan1, dim3(nb1), dim3(TPB), 0, stream, counts, off, blksums, N);
    hipLaunchKernelGGL(k_scan2, dim3(1), dim3(64), 0, stream, blksums, nb1);
    hipLaunchKernelGGL(k_scan3, dim3(nbt), dim3(TPB), 0, stream, off, blksums, cur, N, E);
    hipLaunchKernelGGL(k_fill,  dim3(pb), dim3(TPB), 0, stream, ei, cur, esrc, E, N);
    hipLaunchKernelGGL(k_agg,   dim3(AGG_BLOCKS), dim3(TPB), 0, stream,
                       xl, off, esrc, W2, b2, out, N);
}

// Round 5
// 279.897 us; speedup vs baseline: 5.1320x; 1.0687x over previous
//
#include <hip/hip_runtime.h>
#include <hip/hip_bf16.h>

#define TPB 256
#define NXCD 8

// f32 -> bf16 bits, round-to-nearest-even
__device__ __forceinline__ unsigned short f2bf(float f) {
    unsigned int u = __float_as_uint(f);
    u += 0x7fffu + ((u >> 16) & 1u);
    return (unsigned short)(u >> 16);
}
// unpack bf16 pair packed in u32 (elem 2w in low half, 2w+1 in high half)
__device__ __forceinline__ float bflo(unsigned int u) { return __uint_as_float(u << 16); }
__device__ __forceinline__ float bfhi(unsigned int u) { return __uint_as_float(u & 0xffff0000u); }

// ---------------- Kernel 1: xl = x @ W1 + b1 -> packed bf16 [N,64] ----------------
__global__ __launch_bounds__(TPB) void k_gemm1(
    const float* __restrict__ x,   // [N,128]
    const float* __restrict__ W1,  // [128,64]
    const float* __restrict__ b1,  // [64]
    unsigned int* __restrict__ xlb, int N)   // [N,32] u32 (bf16 pairs)
{
    __shared__ float w1s[128 * 64];   // 32 KB
    __shared__ float xs[64 * 132];    // padded stride 132 (2-way alias = free)
    __shared__ float b1s[64];

    const int t = threadIdx.x;
    const int rbase = blockIdx.x * 64;
    const int rows = min(64, N - rbase);

    const float4* w4 = reinterpret_cast<const float4*>(W1);
    for (int i = t; i < 2048; i += TPB) {
        float4 u = w4[i];
        int o = i * 4;
        w1s[o+0] = u.x; w1s[o+1] = u.y; w1s[o+2] = u.z; w1s[o+3] = u.w;
    }
    if (t < 64) b1s[t] = b1[t];

    const float4* x4 = reinterpret_cast<const float4*>(x);
    for (int i = t; i < rows * 32; i += TPB) {
        float4 u = x4[(size_t)rbase * 32 + i];
        int row = i >> 5, kk = (i & 31) * 4;
        float* p = &xs[row * 132 + kk];
        p[0] = u.x; p[1] = u.y; p[2] = u.z; p[3] = u.w;
    }
    __syncthreads();

    const int row = t >> 2, cg = t & 3;   // 4 threads/row, 16 cols each
    if (row < rows) {
        float acc[16];
        #pragma unroll
        for (int c = 0; c < 16; c++) acc[c] = b1s[cg*16 + c];
        const float* xr = &xs[row * 132];
        #pragma unroll 4
        for (int k = 0; k < 128; k++) {
            float a = xr[k];
            const float* wp = &w1s[k*64 + cg*16];
            #pragma unroll
            for (int c = 0; c < 16; c++) acc[c] = fmaf(a, wp[c], acc[c]);
        }
        union { unsigned int u[8]; uint4 v[2]; } pk;
        #pragma unroll
        for (int j = 0; j < 8; j++)
            pk.u[j] = (unsigned int)f2bf(acc[2*j]) | ((unsigned int)f2bf(acc[2*j+1]) << 16);
        uint4* xo = reinterpret_cast<uint4*>(xlb + (size_t)(rbase + row) * 32 + cg * 8);
        xo[0] = pk.v[0];
        xo[1] = pk.v[1];
    }
}

// ---------------- CSR build, XCD-slice-privatized, int4 loads ----------------
__global__ __launch_bounds__(TPB) void k_hist(
    const int* __restrict__ ei, int* __restrict__ counts, int E, int N)
{
    const int slice = (N + NXCD - 1) / NXCD;
    const int g = blockIdx.x & (NXCD - 1);
    const int kb = blockIdx.x >> 3;
    const int K = gridDim.x >> 3;
    const int lo = g * slice, hi = min(N, lo + slice);
    const int4* d4 = reinterpret_cast<const int4*>(ei + E);
    const int E4 = E >> 2;
    for (int i = kb * TPB + threadIdx.x; i < E4; i += K * TPB) {
        int4 d = d4[i];
        if (d.x >= lo && d.x < hi) atomicAdd(&counts[d.x], 1);
        if (d.y >= lo && d.y < hi) atomicAdd(&counts[d.y], 1);
        if (d.z >= lo && d.z < hi) atomicAdd(&counts[d.z], 1);
        if (d.w >= lo && d.w < hi) atomicAdd(&counts[d.w], 1);
    }
    if (g == 0 && kb == 0) {   // tail if E % 4 != 0
        for (int i = (E4 << 2) + threadIdx.x; i < E; i += TPB) {
            int d = ei[E + i];
            atomicAdd(&counts[d], 1);
        }
    }
}

#define SCAN_CHUNK 8
#define SCAN_ELEMS (TPB * SCAN_CHUNK)
__global__ __launch_bounds__(TPB) void k_scan1(
    const int* __restrict__ counts, int* __restrict__ off,
    int* __restrict__ blksums, int N)
{
    __shared__ int wsum[4];
    const int t = threadIdx.x;
    const int base = blockIdx.x * SCAN_ELEMS + t * SCAN_CHUNK;
    int v[SCAN_CHUNK];
    #pragma unroll
    for (int j = 0; j < SCAN_CHUNK; j++)
        v[j] = (base + j < N) ? counts[base + j] : 0;
    int tsum = 0;
    #pragma unroll
    for (int j = 0; j < SCAN_CHUNK; j++) { int a = v[j]; v[j] = tsum; tsum += a; }
    const int lane = t & 63, wid = t >> 6;
    int incl = tsum;
    for (int d = 1; d < 64; d <<= 1) {
        int n = __shfl_up(incl, d);
        if (lane >= d) incl += n;
    }
    if (lane == 63) wsum[wid] = incl;
    __syncthreads();
    int woff = 0;
    for (int w = 0; w < wid; w++) woff += wsum[w];
    const int texcl = woff + incl - tsum;
    #pragma unroll
    for (int j = 0; j < SCAN_CHUNK; j++)
        if (base + j < N) off[base + j] = v[j] + texcl;
    if (t == TPB - 1) blksums[blockIdx.x] = woff + incl;
}

// adds cross-block prefix (computed per-block from blksums, <=49 entries),
// duplicates into cursor array, sets off[N]=E.  (replaces old serial scan2)
__global__ __launch_bounds__(TPB) void k_scan3(
    int* __restrict__ off, const int* __restrict__ blksums,
    int* __restrict__ cur, int N, int E)
{
    __shared__ int base_s;
    const int t = threadIdx.x;
    const int bb = (blockIdx.x * TPB) / SCAN_ELEMS;  // all elems of this block share it
    if (t < 64) {
        int v = 0;
        for (int j = t; j < bb; j += 64) v += blksums[j];
        #pragma unroll
        for (int d = 32; d >= 1; d >>= 1) v += __shfl_xor(v, d);
        if (t == 0) base_s = v;
    }
    __syncthreads();
    int i = blockIdx.x * TPB + t;
    if (i < N) {
        int v = off[i] + base_s;
        off[i] = v;
        cur[i] = v;
    }
    if (i == 0) off[N] = E;
}

__global__ __launch_bounds__(TPB) void k_fill(
    const int* __restrict__ ei, int* __restrict__ cur,
    int* __restrict__ esrc, int E, int N)
{
    const int slice = (N + NXCD - 1) / NXCD;
    const int g = blockIdx.x & (NXCD - 1);
    const int kb = blockIdx.x >> 3;
    const int K = gridDim.x >> 3;
    const int lo = g * slice, hi = min(N, lo + slice);
    const int4* d4 = reinterpret_cast<const int4*>(ei + E);
    const int4* s4 = reinterpret_cast<const int4*>(ei);
    const int E4 = E >> 2;
    for (int i = kb * TPB + threadIdx.x; i < E4; i += K * TPB) {
        int4 d = d4[i];
        int4 s = s4[i];
        if (d.x >= lo && d.x < hi) esrc[atomicAdd(&cur[d.x], 1)] = s.x;
        if (d.y >= lo && d.y < hi) esrc[atomicAdd(&cur[d.y], 1)] = s.y;
        if (d.z >= lo && d.z < hi) esrc[atomicAdd(&cur[d.z], 1)] = s.z;
        if (d.w >= lo && d.w < hi) esrc[atomicAdd(&cur[d.w], 1)] = s.w;
    }
    if (g == 0 && kb == 0) {   // tail
        for (int i = (E4 << 2) + threadIdx.x; i < E; i += TPB) {
            int d = ei[E + i];
            esrc[atomicAdd(&cur[d], 1)] = ei[i];
        }
    }
}

// ---------------- Aggregate (bf16 gather) + ReLU + GEMM2 fused ----------------
// one wave per node: 8 edge-slots x 8 lanes, each lane loads uint4 = 8 bf16
// features; f32 accumulate; shuffle-reduce across slots; self-loop; relu ->
// wave-private LDS row -> gemm2 -> out
#define AGG_BLOCKS 2048
__global__ __launch_bounds__(TPB) void k_agg(
    const unsigned int* __restrict__ xlb,  // [N,32] u32 (bf16 pairs)
    const int* __restrict__ off,           // [N+1]
    const int* __restrict__ esrc,          // [E]
    const float* __restrict__ W2,          // [64,32]
    const float* __restrict__ b2,          // [32]
    float* __restrict__ out, int N)
{
    __shared__ float w2s[64 * 32];   // 8 KB
    __shared__ float b2s[32];
    __shared__ float arow[4][68];    // wave-private agg row

    const int t = threadIdx.x;
    const float4* w4 = reinterpret_cast<const float4*>(W2);
    for (int i = t; i < 512; i += TPB) {
        float4 u = w4[i];
        int o = i * 4;
        w2s[o+0] = u.x; w2s[o+1] = u.y; w2s[o+2] = u.z; w2s[o+3] = u.w;
    }
    if (t < 32) b2s[t] = b2[t];
    __syncthreads();

    const int wid = t >> 6, lane = t & 63;
    const int slot = lane >> 3, b = lane & 7;     // 8 edge slots x 8 lanes
    const int c = lane & 31, h = lane >> 5;       // gemm2 mapping
    const uint4* xb4 = reinterpret_cast<const uint4*>(xlb);

    for (int node = blockIdx.x * 4 + wid; node < N; node += gridDim.x * 4) {
        const int beg = off[node], end = off[node + 1];
        float a0=0.f,a1=0.f,a2=0.f,a3=0.f,a4=0.f,a5=0.f,a6=0.f,a7=0.f;
        for (int e = beg + slot; e < end; e += 8) {
            int s = esrc[e];
            uint4 v = xb4[(size_t)s * 8 + b];
            a0 += bflo(v.x); a1 += bfhi(v.x);
            a2 += bflo(v.y); a3 += bfhi(v.y);
            a4 += bflo(v.z); a5 += bfhi(v.z);
            a6 += bflo(v.w); a7 += bfhi(v.w);
        }
        // reduce across the 8 edge slots (lane bits 3,4,5)
        #pragma unroll
        for (int d = 8; d <= 32; d <<= 1) {
            a0 += __shfl_xor(a0, d); a1 += __shfl_xor(a1, d);
            a2 += __shfl_xor(a2, d); a3 += __shfl_xor(a3, d);
            a4 += __shfl_xor(a4, d); a5 += __shfl_xor(a5, d);
            a6 += __shfl_xor(a6, d); a7 += __shfl_xor(a7, d);
        }
        if (slot == 0) {
            uint4 sv = xb4[(size_t)node * 8 + b];   // self-loop
            float* p = &arow[wid][b * 8];
            p[0] = fmaxf(a0 + bflo(sv.x), 0.f);
            p[1] = fmaxf(a1 + bfhi(sv.x), 0.f);
            p[2] = fmaxf(a2 + bflo(sv.y), 0.f);
            p[3] = fmaxf(a3 + bfhi(sv.y), 0.f);
            p[4] = fmaxf(a4 + bflo(sv.z), 0.f);
            p[5] = fmaxf(a5 + bfhi(sv.z), 0.f);
            p[6] = fmaxf(a6 + bflo(sv.w), 0.f);
            p[7] = fmaxf(a7 + bfhi(sv.w), 0.f);
        }
        // same-wave LDS RAW: in-order LDS pipe + compiler lgkmcnt wait
        float o = 0.f;
        const float* ar = &arow[wid][h * 32];
        const float* wp = &w2s[h * 32 * 32 + c];
        #pragma unroll
        for (int kk = 0; kk < 32; kk++)
            o = fmaf(ar[kk], wp[kk * 32], o);
        o += __shfl_xor(o, 32);
        if (h == 0) out[(size_t)node * 32 + c] = o + b2s[c];
    }
}

extern "C" void kernel_launch(void* const* d_in, const int* in_sizes, int n_in,
                              void* d_out, int out_size, void* d_ws, size_t ws_size,
                              hipStream_t stream) {
    const float* x  = (const float*)d_in[0];
    const int*   ei = (const int*)d_in[1];
    const float* W1 = (const float*)d_in[2];
    const float* b1 = (const float*)d_in[3];
    const float* W2 = (const float*)d_in[4];
    const float* b2 = (const float*)d_in[5];
    float* out = (float*)d_out;

    const int N = in_sizes[0] / 128;
    const int E = in_sizes[1] / 2;

    char* w = (char*)d_ws;
    unsigned int* xlb = (unsigned int*)w;      w += (size_t)N * 32 * 4;   // 12.8 MB
    int* counts = (int*)w;                     w += ((size_t)N * 4 + 15) & ~15ull;
    int* off    = (int*)w;                     w += ((size_t)(N + 1) * 4 + 15) & ~15ull;
    int* cur    = (int*)w;                     w += ((size_t)N * 4 + 15) & ~15ull;
    int* blksums= (int*)w;                     w += 4096;
    int* esrc   = (int*)w;                     // E*4 = 6.4 MB

    const int nb  = (N + 63) / 64;
    const int nb1 = (N + SCAN_ELEMS - 1) / SCAN_ELEMS;
    const int nbt = (N + TPB - 1) / TPB;
    const int pb  = 2048;   // privatized kernels: 8 groups x 256 blocks

    hipMemsetAsync(counts, 0, (size_t)N * 4, stream);
    hipLaunchKernelGGL(k_gemm1, dim3(nb), dim3(TPB), 0, stream, x, W1, b1, xlb, N);
    hipLaunchKernelGGL(k_hist,  dim3(pb), dim3(TPB), 0, stream, ei, counts, E, N);
    hipLaunchKernelGGL(k_scan1, dim3(nb1), dim3(TPB), 0, stream, counts, off, blksums, N);
    hipLaunchKernelGGL(k_scan3, dim3(nbt), dim3(TPB), 0, stream, off, blksums, cur, N, E);
    hipLaunchKernelGGL(k_fill,  dim3(pb), dim3(TPB), 0, stream, ei, cur, esrc, E, N);
    hipLaunchKernelGGL(k_agg,   dim3(AGG_BLOCKS), dim3(TPB), 0, stream,
                       xlb, off, esrc, W2, b2, out, N);
}

// Round 7
// 272.866 us; speedup vs baseline: 5.2643x; 1.0258x over previous
//
#include <hip/hip_runtime.h>
#include <hip/hip_bf16.h>

#define TPB 256
#define NXCD 8

typedef int vint4 __attribute__((ext_vector_type(4)));   // native vec, ok for nontemporal builtin

// f32 -> bf16 bits, round-to-nearest-even
__device__ __forceinline__ unsigned short f2bf(float f) {
    unsigned int u = __float_as_uint(f);
    u += 0x7fffu + ((u >> 16) & 1u);
    return (unsigned short)(u >> 16);
}
// unpack bf16 pair packed in u32
__device__ __forceinline__ float bflo(unsigned int u) { return __uint_as_float(u << 16); }
__device__ __forceinline__ float bfhi(unsigned int u) { return __uint_as_float(u & 0xffff0000u); }

// ---------------- Kernel 1: xl = x @ W1 + b1 -> packed bf16 [N,64] ----------------
__global__ __launch_bounds__(TPB) void k_gemm1(
    const float* __restrict__ x,   // [N,128]
    const float* __restrict__ W1,  // [128,64]
    const float* __restrict__ b1,  // [64]
    unsigned int* __restrict__ xlb, int N)   // [N,32] u32 (bf16 pairs)
{
    __shared__ float w1s[128 * 64];
    __shared__ float xs[64 * 132];
    __shared__ float b1s[64];

    const int t = threadIdx.x;
    const int rbase = blockIdx.x * 64;
    const int rows = min(64, N - rbase);

    const float4* w4 = reinterpret_cast<const float4*>(W1);
    for (int i = t; i < 2048; i += TPB) {
        float4 u = w4[i];
        int o = i * 4;
        w1s[o+0] = u.x; w1s[o+1] = u.y; w1s[o+2] = u.z; w1s[o+3] = u.w;
    }
    if (t < 64) b1s[t] = b1[t];

    const float4* x4 = reinterpret_cast<const float4*>(x);
    for (int i = t; i < rows * 32; i += TPB) {
        float4 u = x4[(size_t)rbase * 32 + i];
        int row = i >> 5, kk = (i & 31) * 4;
        float* p = &xs[row * 132 + kk];
        p[0] = u.x; p[1] = u.y; p[2] = u.z; p[3] = u.w;
    }
    __syncthreads();

    const int row = t >> 2, cg = t & 3;
    if (row < rows) {
        float acc[16];
        #pragma unroll
        for (int c = 0; c < 16; c++) acc[c] = b1s[cg*16 + c];
        const float* xr = &xs[row * 132];
        #pragma unroll 4
        for (int k = 0; k < 128; k++) {
            float a = xr[k];
            const float* wp = &w1s[k*64 + cg*16];
            #pragma unroll
            for (int c = 0; c < 16; c++) acc[c] = fmaf(a, wp[c], acc[c]);
        }
        union { unsigned int u[8]; uint4 v[2]; } pk;
        #pragma unroll
        for (int j = 0; j < 8; j++)
            pk.u[j] = (unsigned int)f2bf(acc[2*j]) | ((unsigned int)f2bf(acc[2*j+1]) << 16);
        uint4* xo = reinterpret_cast<uint4*>(xlb + (size_t)(rbase + row) * 32 + cg * 8);
        xo[0] = pk.v[0];
        xo[1] = pk.v[1];
    }
}

// ---------------- CSR build, XCD-slice-privatized ----------------
// ei streaming loads are NON-TEMPORAL: each group pulls 12.8 MB through its
// XCD's 4 MB L2; without nt this evicts the dirty counts/cur/esrc lines
// (observed 12x write amplification on esrc). nt = no L2 allocation.
__global__ __launch_bounds__(TPB) void k_hist(
    const int* __restrict__ ei, int* __restrict__ counts, int E, int N)
{
    const int slice = (N + NXCD - 1) / NXCD;
    const int g = blockIdx.x & (NXCD - 1);
    const int kb = blockIdx.x >> 3;
    const int K = gridDim.x >> 3;
    const int lo = g * slice, hi = min(N, lo + slice);
    const vint4* d4 = reinterpret_cast<const vint4*>(ei + E);
    const int E4 = E >> 2;
    for (int i = kb * TPB + threadIdx.x; i < E4; i += K * TPB) {
        vint4 d = __builtin_nontemporal_load(&d4[i]);
        if (d.x >= lo && d.x < hi) atomicAdd(&counts[d.x], 1);
        if (d.y >= lo && d.y < hi) atomicAdd(&counts[d.y], 1);
        if (d.z >= lo && d.z < hi) atomicAdd(&counts[d.z], 1);
        if (d.w >= lo && d.w < hi) atomicAdd(&counts[d.w], 1);
    }
    if (g == 0 && kb == 0) {
        for (int i = (E4 << 2) + threadIdx.x; i < E; i += TPB)
            atomicAdd(&counts[ei[E + i]], 1);
    }
}

#define SCAN_CHUNK 8
#define SCAN_ELEMS (TPB * SCAN_CHUNK)
__global__ __launch_bounds__(TPB) void k_scan1(
    const int* __restrict__ counts, int* __restrict__ off,
    int* __restrict__ blksums, int N)
{
    __shared__ int wsum[4];
    const int t = threadIdx.x;
    const int base = blockIdx.x * SCAN_ELEMS + t * SCAN_CHUNK;
    int v[SCAN_CHUNK];
    #pragma unroll
    for (int j = 0; j < SCAN_CHUNK; j++)
        v[j] = (base + j < N) ? counts[base + j] : 0;
    int tsum = 0;
    #pragma unroll
    for (int j = 0; j < SCAN_CHUNK; j++) { int a = v[j]; v[j] = tsum; tsum += a; }
    const int lane = t & 63, wid = t >> 6;
    int incl = tsum;
    for (int d = 1; d < 64; d <<= 1) {
        int n = __shfl_up(incl, d);
        if (lane >= d) incl += n;
    }
    if (lane == 63) wsum[wid] = incl;
    __syncthreads();
    int woff = 0;
    for (int w = 0; w < wid; w++) woff += wsum[w];
    const int texcl = woff + incl - tsum;
    #pragma unroll
    for (int j = 0; j < SCAN_CHUNK; j++)
        if (base + j < N) off[base + j] = v[j] + texcl;
    if (t == TPB - 1) blksums[blockIdx.x] = woff + incl;
}

__global__ __launch_bounds__(TPB) void k_scan3(
    int* __restrict__ off, const int* __restrict__ blksums,
    int* __restrict__ cur, int N, int E)
{
    __shared__ int base_s;
    const int t = threadIdx.x;
    const int bb = (blockIdx.x * TPB) / SCAN_ELEMS;
    if (t < 64) {
        int v = 0;
        for (int j = t; j < bb; j += 64) v += blksums[j];
        #pragma unroll
        for (int d = 32; d >= 1; d >>= 1) v += __shfl_xor(v, d);
        if (t == 0) base_s = v;
    }
    __syncthreads();
    int i = blockIdx.x * TPB + t;
    if (i < N) {
        int v = off[i] + base_s;
        off[i] = v;
        cur[i] = v;
    }
    if (i == 0) off[N] = E;
}

__global__ __launch_bounds__(TPB) void k_fill(
    const int* __restrict__ ei, int* __restrict__ cur,
    int* __restrict__ esrc, int E, int N)
{
    const int slice = (N + NXCD - 1) / NXCD;
    const int g = blockIdx.x & (NXCD - 1);
    const int kb = blockIdx.x >> 3;
    const int K = gridDim.x >> 3;
    const int lo = g * slice, hi = min(N, lo + slice);
    const vint4* d4 = reinterpret_cast<const vint4*>(ei + E);
    const vint4* s4 = reinterpret_cast<const vint4*>(ei);
    const int E4 = E >> 2;
    for (int i = kb * TPB + threadIdx.x; i < E4; i += K * TPB) {
        vint4 d = __builtin_nontemporal_load(&d4[i]);
        vint4 s = __builtin_nontemporal_load(&s4[i]);
        if (d.x >= lo && d.x < hi) esrc[atomicAdd(&cur[d.x], 1)] = s.x;
        if (d.y >= lo && d.y < hi) esrc[atomicAdd(&cur[d.y], 1)] = s.y;
        if (d.z >= lo && d.z < hi) esrc[atomicAdd(&cur[d.z], 1)] = s.z;
        if (d.w >= lo && d.w < hi) esrc[atomicAdd(&cur[d.w], 1)] = s.w;
    }
    if (g == 0 && kb == 0) {
        for (int i = (E4 << 2) + threadIdx.x; i < E; i += TPB) {
            int d = ei[E + i];
            esrc[atomicAdd(&cur[d], 1)] = ei[i];
        }
    }
}

// ---------------- Aggregate (bf16 gather) + ReLU + GEMM2 fused ----------------
// 2-deep unrolled edge loop: both esrc loads + both row-gathers in flight
// (dependent chains were ~2 sequential iterations at avg degree 16).
#define AGG_BLOCKS 2048
__global__ __launch_bounds__(TPB) void k_agg(
    const unsigned int* __restrict__ xlb,  // [N,32] u32 (bf16 pairs)
    const int* __restrict__ off,           // [N+1]
    const int* __restrict__ esrc,          // [E]
    const float* __restrict__ W2,          // [64,32]
    const float* __restrict__ b2,          // [32]
    float* __restrict__ out, int N)
{
    __shared__ float w2s[64 * 32];
    __shared__ float b2s[32];
    __shared__ float arow[4][68];

    const int t = threadIdx.x;
    const float4* w4 = reinterpret_cast<const float4*>(W2);
    for (int i = t; i < 512; i += TPB) {
        float4 u = w4[i];
        int o = i * 4;
        w2s[o+0] = u.x; w2s[o+1] = u.y; w2s[o+2] = u.z; w2s[o+3] = u.w;
    }
    if (t < 32) b2s[t] = b2[t];
    __syncthreads();

    const int wid = t >> 6, lane = t & 63;
    const int slot = lane >> 3, b = lane & 7;
    const int c = lane & 31, h = lane >> 5;
    const uint4* xb4 = reinterpret_cast<const uint4*>(xlb);

    for (int node = blockIdx.x * 4 + wid; node < N; node += gridDim.x * 4) {
        const int beg = off[node], end = off[node + 1];
        float a0=0.f,a1=0.f,a2=0.f,a3=0.f,a4=0.f,a5=0.f,a6=0.f,a7=0.f;
        int e = beg + slot;
        for (; e + 8 < end; e += 16) {
            int s0 = esrc[e];
            int s1 = esrc[e + 8];
            uint4 v0 = xb4[(size_t)s0 * 8 + b];
            uint4 v1 = xb4[(size_t)s1 * 8 + b];
            a0 += bflo(v0.x); a1 += bfhi(v0.x);
            a2 += bflo(v0.y); a3 += bfhi(v0.y);
            a4 += bflo(v0.z); a5 += bfhi(v0.z);
            a6 += bflo(v0.w); a7 += bfhi(v0.w);
            a0 += bflo(v1.x); a1 += bfhi(v1.x);
            a2 += bflo(v1.y); a3 += bfhi(v1.y);
            a4 += bflo(v1.z); a5 += bfhi(v1.z);
            a6 += bflo(v1.w); a7 += bfhi(v1.w);
        }
        if (e < end) {
            int s = esrc[e];
            uint4 v = xb4[(size_t)s * 8 + b];
            a0 += bflo(v.x); a1 += bfhi(v.x);
            a2 += bflo(v.y); a3 += bfhi(v.y);
            a4 += bflo(v.z); a5 += bfhi(v.z);
            a6 += bflo(v.w); a7 += bfhi(v.w);
        }
        #pragma unroll
        for (int d = 8; d <= 32; d <<= 1) {
            a0 += __shfl_xor(a0, d); a1 += __shfl_xor(a1, d);
            a2 += __shfl_xor(a2, d); a3 += __shfl_xor(a3, d);
            a4 += __shfl_xor(a4, d); a5 += __shfl_xor(a5, d);
            a6 += __shfl_xor(a6, d); a7 += __shfl_xor(a7, d);
        }
        if (slot == 0) {
            uint4 sv = xb4[(size_t)node * 8 + b];
            float* p = &arow[wid][b * 8];
            p[0] = fmaxf(a0 + bflo(sv.x), 0.f);
            p[1] = fmaxf(a1 + bfhi(sv.x), 0.f);
            p[2] = fmaxf(a2 + bflo(sv.y), 0.f);
            p[3] = fmaxf(a3 + bfhi(sv.y), 0.f);
            p[4] = fmaxf(a4 + bflo(sv.z), 0.f);
            p[5] = fmaxf(a5 + bfhi(sv.z), 0.f);
            p[6] = fmaxf(a6 + bflo(sv.w), 0.f);
            p[7] = fmaxf(a7 + bfhi(sv.w), 0.f);
        }
        float o = 0.f;
        const float* ar = &arow[wid][h * 32];
        const float* wp = &w2s[h * 32 * 32 + c];
        #pragma unroll
        for (int kk = 0; kk < 32; kk++)
            o = fmaf(ar[kk], wp[kk * 32], o);
        o += __shfl_xor(o, 32);
        if (h == 0) out[(size_t)node * 32 + c] = o + b2s[c];
    }
}

extern "C" void kernel_launch(void* const* d_in, const int* in_sizes, int n_in,
                              void* d_out, int out_size, void* d_ws, size_t ws_size,
                              hipStream_t stream) {
    const float* x  = (const float*)d_in[0];
    const int*   ei = (const int*)d_in[1];
    const float* W1 = (const float*)d_in[2];
    const float* b1 = (const float*)d_in[3];
    const float* W2 = (const float*)d_in[4];
    const float* b2 = (const float*)d_in[5];
    float* out = (float*)d_out;

    const int N = in_sizes[0] / 128;
    const int E = in_sizes[1] / 2;

    char* w = (char*)d_ws;
    unsigned int* xlb = (unsigned int*)w;      w += (size_t)N * 32 * 4;   // 12.8 MB
    int* counts = (int*)w;                     w += ((size_t)N * 4 + 15) & ~15ull;
    int* off    = (int*)w;                     w += ((size_t)(N + 1) * 4 + 15) & ~15ull;
    int* cur    = (int*)w;                     w += ((size_t)N * 4 + 15) & ~15ull;
    int* blksums= (int*)w;                     w += 4096;
    int* esrc   = (int*)w;                     // E*4 = 6.4 MB

    const int nb  = (N + 63) / 64;
    const int nb1 = (N + SCAN_ELEMS - 1) / SCAN_ELEMS;
    const int nbt = (N + TPB - 1) / TPB;
    const int pb  = 2048;

    (void)hipMemsetAsync(counts, 0, (size_t)N * 4, stream);
    hipLaunchKernelGGL(k_gemm1, dim3(nb), dim3(TPB), 0, stream, x, W1, b1, xlb, N);
    hipLaunchKernelGGL(k_hist,  dim3(pb), dim3(TPB), 0, stream, ei, counts, E, N);
    hipLaunchKernelGGL(k_scan1, dim3(nb1), dim3(TPB), 0, stream, counts, off, blksums, N);
    hipLaunchKernelGGL(k_scan3, dim3(nbt), dim3(TPB), 0, stream, off, blksums, cur, N, E);
    hipLaunchKernelGGL(k_fill,  dim3(pb), dim3(TPB), 0, stream, ei, cur, esrc, E, N);
    hipLaunchKernelGGL(k_agg,   dim3(AGG_BLOCKS), dim3(TPB), 0, stream,
                       xlb, off, esrc, W2, b2, out, N);
}